// Round 6
// baseline (220.009 us; speedup 1.0000x reference)
//
#include <hip/hip_runtime.h>
#include <stdint.h>

// ---------------------------------------------------------------------------
// MixingLayer: b=16, m=64, f=128, k=64, L2=16, LMAX=4. ALL I/O IS FP32.
// SEG = [0,1,1,1,2,2,2,2,2,3,3,3,3,3,3,3]
//
// G is never materialized. fused_gemm recomputes the 128x32 A-tile per step:
//   mx/my[m,n] = sum_kk G[m][kk] * W[n][kk],  kk = fy*512 + fx*4 + l
//   G[m][kk]   = sum_c y[m,fy,c] * x[m,fx,c] * S[c,l]
// Round-6 vs round-5 (which was grid-capped at 2 blocks/CU):
//   * grid (128 splits x 8 M-tiles) = 1024 blocks -> 4 blocks/CU (LDS cap)
//   * split = 1 fy, 16 steps of BK=32
//   * sB XOR swizzle (DMA-compatible: permute source col per lane) kills the
//     8-way bank conflict on B-fragment ds_read_b128
//   * grid order (split fastest) -> all 8 blocks of a split on one XCD:
//     split's 256KB Wb slab stays L2-resident
//
// ws layout (bytes):
//   Wb  bf16 [128 n][65536 kk]   @ 0          (16,777,216)
//   xb  bf16 [1024 m][128 f][16] @ 16777216   ( 4,194,304)
//   yb  bf16 [1024 m][128 f][16] @ 20971520   ( 4,194,304)
//   Cpart f32 [128][1024][128]   @ 25165824   (67,108,864)
//   wfT f32 [2][64 k][4 l][128f] @ 92274688   (   262,144)
// ---------------------------------------------------------------------------

#define AS1 __attribute__((address_space(1)))
#define AS3 __attribute__((address_space(3)))

typedef __bf16 bf16x8 __attribute__((ext_vector_type(8)));
typedef float f32x4 __attribute__((ext_vector_type(4)));

__device__ __forceinline__ uint16_t f2b(float f) {
  uint32_t u = __float_as_uint(f);
  u += 0x7fffu + ((u >> 16) & 1u);   // RNE
  return (uint16_t)(u >> 16);
}

__device__ __forceinline__ void up2(uint32_t d, float& lo, float& hi) {
  lo = __uint_as_float(d << 16);
  hi = __uint_as_float(d & 0xffff0000u);
}
__device__ __forceinline__ void up8(uint4 v, float* o) {
  up2(v.x, o[0], o[1]); up2(v.y, o[2], o[3]);
  up2(v.z, o[4], o[5]); up2(v.w, o[6], o[7]);
}

// ---------------------------------------------------------------------------
// K0: one-shot f32 -> bf16 conversions: Wb (wx0|wy0), xb, yb.
// ---------------------------------------------------------------------------
__global__ __launch_bounds__(256) void convert_all(
    const float* __restrict__ wx0, const float* __restrict__ wy0,
    const float* __restrict__ x, const float* __restrict__ y,
    uint16_t* __restrict__ Wb, uint16_t* __restrict__ xb,
    uint16_t* __restrict__ yb) {
  size_t i = ((size_t)blockIdx.x * 256 + threadIdx.x) * 8;
  const float* s; uint16_t* d;
  if (i < 4194304)        { s = wx0 + i;              d = Wb + i; }
  else if (i < 8388608)   { s = wy0 + (i - 4194304);  d = Wb + i; }
  else if (i < 10485760)  { s = x + (i - 8388608);    d = xb + (i - 8388608); }
  else                    { s = y + (i - 10485760);   d = yb + (i - 10485760); }
  float4 v0 = *(const float4*)s;
  float4 v1 = *(const float4*)(s + 4);
  uint32_t o0 = (uint32_t)f2b(v0.x) | ((uint32_t)f2b(v0.y) << 16);
  uint32_t o1 = (uint32_t)f2b(v0.z) | ((uint32_t)f2b(v0.w) << 16);
  uint32_t o2 = (uint32_t)f2b(v1.x) | ((uint32_t)f2b(v1.y) << 16);
  uint32_t o3 = (uint32_t)f2b(v1.z) | ((uint32_t)f2b(v1.w) << 16);
  *(uint4*)d = make_uint4(o0, o1, o2, o3);
}

// ---------------------------------------------------------------------------
// K1: FUSED G-gen + split-K GEMM, double-buffered, 1 barrier/step.
// grid (128 splits, 8 M-tiles), block 256 (2x2 waves of 64x64).
// split s covers fy = s; 16 steps of 8 fx (BK=32 kk).
// sB swizzle: 16B-position p within a row holds col-block c = p ^ ((row>>1)&3).
// ---------------------------------------------------------------------------
__device__ __forceinline__ void gload_lds16(const void* g, void* l) {
  __builtin_amdgcn_global_load_lds((const AS1 uint32_t*)g, (AS3 uint32_t*)l, 16, 0, 0);
}

__global__ __launch_bounds__(256, 4) void fused_gemm(
    const uint16_t* __restrict__ xb, const uint16_t* __restrict__ yb,
    const uint16_t* __restrict__ Wb, float* __restrict__ Cpart) {
  __shared__ __align__(16) uint16_t sA[2][128 * 40];  // padded stride 40
  __shared__ __align__(16) uint16_t sB[2][128 * 32];  // XOR-swizzled cols
  const int seg[16] = {0,1,1,1,2,2,2,2,2,3,3,3,3,3,3,3};

  int tid = threadIdx.x;
  int w = tid >> 6, lane = tid & 63;
  int s = blockIdx.x;                 // split = fy (XCD-local: linear%8 = s%8)
  int m0 = blockIdx.y * 128;
  int r = lane & 15, q = lane >> 4;
  int wm = w >> 1, wn = w & 1;
  int rowl = lane >> 2, qq = lane & 3;
  int m_loc = tid & 127, half = tid >> 7;

  const uint16_t* xrow = xb + (size_t)(m0 + m_loc) * 2048;
  const uint16_t* yrow = yb + (size_t)(m0 + m_loc) * 2048;

  // y[m, fy, 0:16] -> registers (single fy per block)
  float yreg[16];
  {
    uint4 v0 = *(const uint4*)(yrow + s * 16);
    uint4 v1 = *(const uint4*)(yrow + s * 16 + 8);
    up8(v0, yreg); up8(v1, yreg + 8);
  }

  f32x4 zero = {0.f, 0.f, 0.f, 0.f};
  f32x4 acc[4][4];
#pragma unroll
  for (int i = 0; i < 4; ++i)
#pragma unroll
    for (int j = 0; j < 4; ++j) acc[i][j] = zero;

  // per-lane swizzled source column for the B DMA: c = qq ^ ((rowl>>1)&3)
  int bcol = qq ^ ((rowl >> 1) & 3);

  auto issueB = [&](int buf, int t) {
    int kk0 = s * 512 + t * 32;
#pragma unroll
    for (int jj = 0; jj < 2; ++jj) {
      int blk = w * 2 + jj;  // wave-uniform
      int rowi = blk * 16 + rowl;
      gload_lds16(Wb + (size_t)rowi * 65536 + kk0 + bcol * 8, &sB[buf][blk * 512]);
    }
  };
  auto computeG = [&](int t, float* g) {
    const uint16_t* xp = xrow + (t * 8 + half * 4) * 16;  // one 128B line
#pragma unroll
    for (int p = 0; p < 16; ++p) g[p] = 0.f;
#pragma unroll
    for (int fxp = 0; fxp < 4; ++fxp) {
      uint4 v0 = *(const uint4*)(xp + fxp * 16);
      uint4 v1 = *(const uint4*)(xp + fxp * 16 + 8);
      float xv[16];
      up8(v0, xv); up8(v1, xv + 8);
#pragma unroll
      for (int c = 0; c < 16; ++c)
        g[fxp * 4 + seg[c]] += yreg[c] * xv[c];
    }
  };
  auto writeA = [&](int buf, const float* g) {
    uint32_t o[8];
#pragma unroll
    for (int p = 0; p < 8; ++p)
      o[p] = (__float_as_uint(g[2 * p]) >> 16) |
             (__float_as_uint(g[2 * p + 1]) & 0xffff0000u);
    uint16_t* dst = &sA[buf][m_loc * 40 + half * 16];
    *(uint4*)dst       = make_uint4(o[0], o[1], o[2], o[3]);
    *(uint4*)(dst + 8) = make_uint4(o[4], o[5], o[6], o[7]);
  };

  // prologue: fill buffer 0 for step 0
  float g[16];
  issueB(0, 0);
  computeG(0, g);
  writeA(0, g);
  __syncthreads();  // drains DMA (vmcnt0) + LDS writes

  for (int t = 0; t < 16; ++t) {
    int cur = t & 1, nxt = cur ^ 1;
    if (t < 15) {
      issueB(nxt, t + 1);      // DMA in flight across this step's compute
      computeG(t + 1, g);
      writeA(nxt, g);
    }
    bf16x8 a[4], b[4];
#pragma unroll
    for (int i = 0; i < 4; ++i)
      a[i] = *(const bf16x8*)&sA[cur][(wm * 64 + i * 16 + r) * 40 + q * 8];
#pragma unroll
    for (int j = 0; j < 4; ++j) {
      int row = wn * 64 + j * 16 + r;
      int pos = q ^ ((row >> 1) & 3);        // un-swizzle
      b[j] = *(const bf16x8*)&sB[cur][row * 32 + pos * 8];
    }
#pragma unroll
    for (int i = 0; i < 4; ++i)
#pragma unroll
      for (int j = 0; j < 4; ++j)
        acc[i][j] = __builtin_amdgcn_mfma_f32_16x16x32_bf16(a[i], b[j], acc[i][j], 0, 0, 0);
    __syncthreads();  // one barrier per step
  }

  // C/D layout: col(n)=lane&15, row(m)=(lane>>4)*4+reg
  float* cbase = Cpart + (size_t)blockIdx.x * 131072;  // 1024*128 per split
#pragma unroll
  for (int i = 0; i < 4; ++i)
#pragma unroll
    for (int j = 0; j < 4; ++j)
#pragma unroll
      for (int reg = 0; reg < 4; ++reg) {
        int mm = m0 + wm * 64 + i * 16 + q * 4 + reg;
        int nn = wn * 64 + j * 16 + r;
        cbase[(size_t)mm * 128 + nn] = acc[i][j][reg];
      }
}

// ---------------------------------------------------------------------------
// K2: wfT[((side*64+k)*4+l)*128+f] = wf_side[(l*128+f)*64+k]  (256 KB)
// ---------------------------------------------------------------------------
__global__ __launch_bounds__(256) void wft_kernel(const float* __restrict__ wxf,
                                                  const float* __restrict__ wyf,
                                                  float* __restrict__ wfT) {
  int idx = blockIdx.x * 256 + threadIdx.x;   // 65536 total
  int side = idx >> 15;
  int rem = idx & 32767;
  int k = rem >> 9;
  int l = (rem >> 7) & 3;
  int f = rem & 127;
  const float* src = side ? wyf : wxf;
  wfT[idx] = src[((size_t)l * 128 + f) * 64 + k];
}

// ---------------------------------------------------------------------------
// K3: ONE BLOCK PER bm (1024 blocks): reduce 128 splits (all 256 threads),
// 2 MLP stages (bias[st][m][j], m=bm&63), gates via wfT, fused output.
// ---------------------------------------------------------------------------
__global__ __launch_bounds__(256) void finish_kernel(
    const float* __restrict__ x, const float* __restrict__ y,
    const float* __restrict__ wx_mlp, const float* __restrict__ bx_mlp,
    const float* __restrict__ wy_mlp, const float* __restrict__ by_mlp,
    const float* __restrict__ wfT,
    const float* __restrict__ Cpart, float* __restrict__ out) {
  const int seg[16] = {0,1,1,1,2,2,2,2,2,3,3,3,3,3,3,3};
  __shared__ float sred[256];
  __shared__ float sm[128];
  __shared__ float sg[2][128][4];
  int t = threadIdx.x;
  int bm = blockIdx.x;
  int mi = bm & 63;

  {  // split-K reduce: 256 threads, each sums 64 of the 128 partials
    int col = t & 127, hh = t >> 7;
    float ssum = 0.f;
#pragma unroll 8
    for (int sp = hh * 64; sp < hh * 64 + 64; ++sp)
      ssum += Cpart[(size_t)sp * 131072 + (size_t)bm * 128 + col];
    sred[t] = ssum;
  }
  __syncthreads();
  if (t < 128) sm[t] = sred[t] + sred[t + 128];  // [0:64)=mx, [64:128)=my
  __syncthreads();

  for (int st = 0; st < 2; ++st) {
    float v = 0.f;
    if (t < 128) {
      int side = t >> 6, j = t & 63;
      const float* wmlp = side ? wy_mlp : wx_mlp;
      const float* bmlp = side ? by_mlp : bx_mlp;
      const float* mv = sm + side * 64;
#pragma unroll 8
      for (int k = 0; k < 64; ++k)
        v += mv[k] * wmlp[(st * 64 + k) * 64 + j];
      v += bmlp[(st * 64 + mi) * 64 + j];
      v = v / (1.f + __expf(-v));
    }
    __syncthreads();
    if (t < 128) sm[t] = v;
    __syncthreads();
  }

  {  // gates: side wave-uniform, coalesced wfT reads
    int side = t >> 7, f = t & 127;
    const float* base = wfT + side * 32768;  // [k][l][f]
    const float* mv = sm + side * 64;
    float g[4] = {0.f, 0.f, 0.f, 0.f};
#pragma unroll 8
    for (int k = 0; k < 64; ++k) {
      float m2 = mv[k];
#pragma unroll
      for (int l = 0; l < 4; ++l)
        g[l] += m2 * base[(k * 4 + l) * 128 + f];
    }
#pragma unroll
    for (int l = 0; l < 4; ++l)
      sg[side][f][l] = g[l] / (1.f + __expf(-g[l]));
  }
  __syncthreads();

  {  // output: thread -> (f, half), 8 floats; fully coalesced
    int f = t >> 1, half = t & 1;
    size_t base = ((size_t)bm * 128 + f) * 16 + half * 8;
    float4 xa = *(const float4*)(x + base), xb4 = *(const float4*)(x + base + 4);
    float4 ya = *(const float4*)(y + base), yb4 = *(const float4*)(y + base + 4);
    float xv[8] = {xa.x, xa.y, xa.z, xa.w, xb4.x, xb4.y, xb4.z, xb4.w};
    float yv[8] = {ya.x, ya.y, ya.z, ya.w, yb4.x, yb4.y, yb4.z, yb4.w};
    float o[8];
#pragma unroll
    for (int ii = 0; ii < 8; ++ii) {
      int c = half * 8 + ii;
      o[ii] = sg[0][f][seg[c]] * xv[ii] + sg[1][f][seg[c]] * yv[ii];
    }
    *(float4*)(out + base)     = make_float4(o[0], o[1], o[2], o[3]);
    *(float4*)(out + base + 4) = make_float4(o[4], o[5], o[6], o[7]);
  }
}

// ---------------------------------------------------------------------------
extern "C" void kernel_launch(void* const* d_in, const int* in_sizes, int n_in,
                              void* d_out, int out_size, void* d_ws, size_t ws_size,
                              hipStream_t stream) {
  const float* x      = (const float*)d_in[0];
  const float* y      = (const float*)d_in[1];
  const float* wx0    = (const float*)d_in[2];
  const float* wy0    = (const float*)d_in[3];
  const float* wx_mlp = (const float*)d_in[4];
  const float* bx_mlp = (const float*)d_in[5];
  const float* wy_mlp = (const float*)d_in[6];
  const float* by_mlp = (const float*)d_in[7];
  const float* wxf    = (const float*)d_in[8];
  const float* wyf    = (const float*)d_in[9];
  float* out = (float*)d_out;

  uint16_t* Wb    = (uint16_t*)d_ws;                               // 16,777,216 B
  uint16_t* xb    = (uint16_t*)((char*)d_ws + (size_t)16777216);   //  4,194,304 B
  uint16_t* yb    = (uint16_t*)((char*)d_ws + (size_t)20971520);   //  4,194,304 B
  float*    Cpart = (float*)((char*)d_ws + (size_t)25165824);      // 67,108,864 B
  float*    wfT   = (float*)((char*)d_ws + (size_t)92274688);      //    262,144 B

  convert_all<<<6144, 256, 0, stream>>>(wx0, wy0, x, y, Wb, xb, yb);
  fused_gemm<<<dim3(128, 8), 256, 0, stream>>>(xb, yb, Wb, Cpart);
  wft_kernel<<<256, 256, 0, stream>>>(wxf, wyf, wfT);
  finish_kernel<<<1024, 256, 0, stream>>>(x, y, wx_mlp, bx_mlp, wy_mlp, by_mlp,
                                          wfT, Cpart, out);
}

// Round 7
// 183.242 us; speedup vs baseline: 1.2007x; 1.2007x over previous
//
#include <hip/hip_runtime.h>
#include <stdint.h>

// ---------------------------------------------------------------------------
// MixingLayer: b=16, m=64, f=128, k=64, L2=16, LMAX=4. ALL I/O IS FP32.
// SEG = [0,1,1,1,2,2,2,2,2,3,3,3,3,3,3,3]
//
// Round-7 fused GEMM: split = (fx-block fb, fy-group fyg); steps iterate fy.
//   * x[m, 4fx, 16c] packed bf16 in 32 VGPRs per thread, loaded ONCE
//   * y[128m, 16c] per step via lane-scatter global_load_lds (dbuf yS)
//   * G via v_dot2_f32_bf16 (guarded; fma fallback)
//   * sA padded stride 40 (verified), sB XOR-swizzled, XCD-local grid order
// Cpart[128][1024][128] f32 -> reduce_kernel -> Cred[1024][128] -> finish.
//
// ws layout (bytes):
//   Wb  bf16 [128 n][65536 kk]   @ 0          (16,777,216)
//   xb  bf16 [1024 m][128 f][16] @ 16777216   ( 4,194,304)
//   yb  bf16 [1024 m][128 f][16] @ 20971520   ( 4,194,304)
//   Cpart f32 [128][1024][128]   @ 25165824   (67,108,864)
//   wfT f32 [2][64 k][4 l][128f] @ 92274688   (   262,144)
//   Cred f32 [1024][128]         @ 92536832   (   524,288)
// ---------------------------------------------------------------------------

#define AS1 __attribute__((address_space(1)))
#define AS3 __attribute__((address_space(3)))

typedef __bf16 bf16x8 __attribute__((ext_vector_type(8)));
typedef float f32x4 __attribute__((ext_vector_type(4)));

__device__ __forceinline__ uint16_t f2b(float f) {
  uint32_t u = __float_as_uint(f);
  u += 0x7fffu + ((u >> 16) & 1u);   // RNE
  return (uint16_t)(u >> 16);
}

#if __has_builtin(__builtin_amdgcn_fdot2_f32_bf16)
typedef __bf16 bf16x2 __attribute__((ext_vector_type(2)));
__device__ __forceinline__ float dot2b(uint32_t a, uint32_t b, float c) {
  union { uint32_t u; bf16x2 v; } ua, ub;
  ua.u = a; ub.u = b;
  return __builtin_amdgcn_fdot2_f32_bf16(ua.v, ub.v, c, false);
}
#else
__device__ __forceinline__ float dot2b(uint32_t a, uint32_t b, float c) {
  float a0 = __uint_as_float(a << 16), a1 = __uint_as_float(a & 0xffff0000u);
  float b0 = __uint_as_float(b << 16), b1 = __uint_as_float(b & 0xffff0000u);
  return c + a0 * b0 + a1 * b1;
}
#endif

// ---------------------------------------------------------------------------
// K0: f32->bf16 for Wb(wx0|wy0), xb, yb  +  wfT transpose (blocks >= 6144).
// ---------------------------------------------------------------------------
__global__ __launch_bounds__(256) void convert_all(
    const float* __restrict__ wx0, const float* __restrict__ wy0,
    const float* __restrict__ x, const float* __restrict__ y,
    const float* __restrict__ wxf, const float* __restrict__ wyf,
    uint16_t* __restrict__ Wb, uint16_t* __restrict__ xb,
    uint16_t* __restrict__ yb, float* __restrict__ wfT) {
  if (blockIdx.x >= 6144) {  // wfT: 32 blocks x 256 thr x 8 elems = 65536
    int base = (blockIdx.x - 6144) * 2048 + threadIdx.x * 8;
#pragma unroll
    for (int ii = 0; ii < 8; ++ii) {
      int idx = base + ii;
      int side = idx >> 15, rem = idx & 32767;
      int k = rem >> 9, l = (rem >> 7) & 3, f = rem & 127;
      const float* src = side ? wyf : wxf;
      wfT[idx] = src[((size_t)l * 128 + f) * 64 + k];
    }
    return;
  }
  size_t i = ((size_t)blockIdx.x * 256 + threadIdx.x) * 8;
  const float* s; uint16_t* d;
  if (i < 4194304)        { s = wx0 + i;              d = Wb + i; }
  else if (i < 8388608)   { s = wy0 + (i - 4194304);  d = Wb + i; }
  else if (i < 10485760)  { s = x + (i - 8388608);    d = xb + (i - 8388608); }
  else                    { s = y + (i - 10485760);   d = yb + (i - 10485760); }
  float4 v0 = *(const float4*)s;
  float4 v1 = *(const float4*)(s + 4);
  uint32_t o0 = (uint32_t)f2b(v0.x) | ((uint32_t)f2b(v0.y) << 16);
  uint32_t o1 = (uint32_t)f2b(v0.z) | ((uint32_t)f2b(v0.w) << 16);
  uint32_t o2 = (uint32_t)f2b(v1.x) | ((uint32_t)f2b(v1.y) << 16);
  uint32_t o3 = (uint32_t)f2b(v1.z) | ((uint32_t)f2b(v1.w) << 16);
  *(uint4*)d = make_uint4(o0, o1, o2, o3);
}

// ---------------------------------------------------------------------------
// K1: FUSED G-gen + split GEMM.
// grid (128 groups, 8 M-tiles); group g: fb = g>>3 (8 fx), fyg = g&7 (16 fy).
// 16 steps, step t: fy = fyg*16 + t; BK=32 kk = fy*512 + fb*32 + [0,32).
// ---------------------------------------------------------------------------
__device__ __forceinline__ void gload_lds16(const void* g, void* l) {
  __builtin_amdgcn_global_load_lds((const AS1 uint32_t*)g, (AS3 uint32_t*)l, 16, 0, 0);
}

__global__ __launch_bounds__(256, 3) void fused_gemm(
    const uint16_t* __restrict__ xb, const uint16_t* __restrict__ yb,
    const uint16_t* __restrict__ Wb, float* __restrict__ Cpart) {
  __shared__ __align__(16) uint16_t sA[2][128 * 40];  // padded stride 40
  __shared__ __align__(16) uint16_t sB[2][128 * 32];  // XOR-swizzled cols
  __shared__ __align__(16) uint16_t yS[2][2048];      // [chunk(2)][m(128)][8c]

  int tid = threadIdx.x;
  int w = tid >> 6, lane = tid & 63;
  int g_id = blockIdx.x;
  int fb = g_id >> 3, fyg = g_id & 7;
  int FB = fb * 8;                  // first fx of this block
  int fy0 = fyg * 16;
  int m0 = blockIdx.y * 128;
  int r = lane & 15, q = lane >> 4;
  int wm = w >> 1, wn = w & 1;
  int rowl = lane >> 2, qq = lane & 3;
  int m_loc = tid & 127, half = tid >> 7;

  // ---- one-time: x[m, FB+half*4 .. +4, 0:16] packed into 32 dwords
  uint32_t xr[32];
  {
    const uint16_t* xp0 = xb + (size_t)(m0 + m_loc) * 2048 + (FB + half * 4) * 16;
#pragma unroll
    for (int j = 0; j < 8; ++j) {
      uint4 v = *(const uint4*)(xp0 + j * 8);
      xr[j * 4 + 0] = v.x; xr[j * 4 + 1] = v.y;
      xr[j * 4 + 2] = v.z; xr[j * 4 + 3] = v.w;
    }
  }

  f32x4 zero = {0.f, 0.f, 0.f, 0.f};
  f32x4 acc[4][4];
#pragma unroll
  for (int i = 0; i < 4; ++i)
#pragma unroll
    for (int j = 0; j < 4; ++j) acc[i][j] = zero;

  int bcol = qq ^ ((rowl >> 1) & 3);  // swizzled source col for B DMA
  // y DMA lane mapping: wave w -> chunk = w>>1, mbase = (w&1)*64; lane -> m
  int ychunk = w >> 1, ymbase = (w & 1) * 64;
  const uint16_t* ysrc_base = yb + (size_t)(m0 + ymbase + lane) * 2048 + ychunk * 8;
  int ydst_off = ychunk * 1024 + ymbase * 8;  // + lane*8 implied by DMA

  auto issueB = [&](uint16_t* dstB, int t) {
    int kk0 = (fy0 + t) * 512 + FB * 4;
#pragma unroll
    for (int jj = 0; jj < 2; ++jj) {
      int blk = w * 2 + jj;  // wave-uniform
      int rowi = blk * 16 + rowl;
      gload_lds16(Wb + (size_t)rowi * 65536 + kk0 + bcol * 8, dstB + blk * 512);
    }
  };
  auto issueY = [&](uint16_t* dstY, int t) {
    gload_lds16(ysrc_base + (size_t)(fy0 + t) * 16, dstY + ydst_off);
  };
  auto computeG = [&](const uint16_t* srcY, float* gg) {
    uint4 ya = *(const uint4*)(srcY + m_loc * 8);
    uint4 yc = *(const uint4*)(srcY + 1024 + m_loc * 8);
    uint32_t yp[8] = {ya.x, ya.y, ya.z, ya.w, yc.x, yc.y, yc.z, yc.w};
    uint32_t yl0 = yp[0] & 0xffffu, yh0 = yp[0] & 0xffff0000u;
    uint32_t yl4 = yp[4] & 0xffffu, yh4 = yp[4] & 0xffff0000u;
#pragma unroll
    for (int fxp = 0; fxp < 4; ++fxp) {
      const uint32_t* xp = xr + fxp * 8;
      gg[fxp * 4 + 0] = dot2b(xp[0], yl0, 0.f);
      gg[fxp * 4 + 1] = dot2b(xp[1], yp[1], dot2b(xp[0], yh0, 0.f));
      gg[fxp * 4 + 2] = dot2b(xp[4], yl4,
                         dot2b(xp[3], yp[3], dot2b(xp[2], yp[2], 0.f)));
      gg[fxp * 4 + 3] = dot2b(xp[7], yp[7], dot2b(xp[6], yp[6],
                         dot2b(xp[5], yp[5], dot2b(xp[4], yh4, 0.f))));
    }
  };
  auto writeA = [&](uint16_t* dstA, const float* gg) {
    uint32_t o[8];
#pragma unroll
    for (int p = 0; p < 8; ++p)
      o[p] = (__float_as_uint(gg[2 * p]) >> 16) |
             (__float_as_uint(gg[2 * p + 1]) & 0xffff0000u);
    uint16_t* dst = dstA + m_loc * 40 + half * 16;
    *(uint4*)dst       = make_uint4(o[0], o[1], o[2], o[3]);
    *(uint4*)(dst + 8) = make_uint4(o[4], o[5], o[6], o[7]);
  };

  uint16_t *pAc = sA[0], *pAn = sA[1];
  uint16_t *pBc = sB[0], *pBn = sB[1];
  uint16_t *pYc = yS[0], *pYn = yS[1];

  float gg[16];
  // prologue
  issueY(pYc, 0);
  __syncthreads();                 // y(0) landed
  computeG(pYc, gg);
  writeA(pAc, gg);
  issueB(pBc, 0);
  issueY(pYn, 1);
  __syncthreads();                 // sA[0]/sB[0]/y(1) ready

  for (int t = 0; t < 16; ++t) {
    if (t < 15) {
      issueB(pBn, t + 1);
      if (t < 14) issueY(pYc, t + 2);   // overwrites y(t) slot, consumed last step
      computeG(pYn, gg);                // y(t+1), ready since last barrier
      writeA(pAn, gg);
    }
    bf16x8 a[4], b[4];
#pragma unroll
    for (int i = 0; i < 4; ++i)
      a[i] = *(const bf16x8*)&pAc[(wm * 64 + i * 16 + r) * 40 + q * 8];
#pragma unroll
    for (int j = 0; j < 4; ++j) {
      int row = wn * 64 + j * 16 + r;
      int pos = q ^ ((row >> 1) & 3);   // un-swizzle
      b[j] = *(const bf16x8*)&pBc[row * 32 + pos * 8];
    }
#pragma unroll
    for (int i = 0; i < 4; ++i)
#pragma unroll
      for (int j = 0; j < 4; ++j)
        acc[i][j] = __builtin_amdgcn_mfma_f32_16x16x32_bf16(a[i], b[j], acc[i][j], 0, 0, 0);
    __syncthreads();                    // one barrier per step
    uint16_t* tp;
    tp = pAc; pAc = pAn; pAn = tp;
    tp = pBc; pBc = pBn; pBn = tp;
    tp = pYc; pYc = pYn; pYn = tp;
  }

  // C/D layout: col(n)=lane&15, row(m)=(lane>>4)*4+reg
  float* cbase = Cpart + (size_t)g_id * 131072;  // 1024*128 per partial
#pragma unroll
  for (int i = 0; i < 4; ++i)
#pragma unroll
    for (int j = 0; j < 4; ++j)
#pragma unroll
      for (int reg = 0; reg < 4; ++reg) {
        int mm = m0 + wm * 64 + i * 16 + q * 4 + reg;
        int nn = wn * 64 + j * 16 + r;
        cbase[(size_t)mm * 128 + nn] = acc[i][j][reg];
      }
}

// ---------------------------------------------------------------------------
// K2: Cred[bm][n] = sum_{sp<128} Cpart[sp][bm][n].  1024 blocks (one per bm).
// ---------------------------------------------------------------------------
__global__ __launch_bounds__(256) void reduce_kernel(
    const float* __restrict__ Cpart, float* __restrict__ Cred) {
  __shared__ float sred[256];
  int t = threadIdx.x, bm = blockIdx.x;
  int col = t & 127, hh = t >> 7;
  float s = 0.f;
#pragma unroll 8
  for (int sp = hh * 64; sp < hh * 64 + 64; ++sp)
    s += Cpart[(size_t)sp * 131072 + (size_t)bm * 128 + col];
  sred[t] = s;
  __syncthreads();
  if (t < 128) Cred[(size_t)bm * 128 + t] = sred[t] + sred[t + 128];
}

// ---------------------------------------------------------------------------
// K3: ONE BLOCK PER bm: MLP (bias[st][m][j], m=bm&63), gates via wfT, output.
// ---------------------------------------------------------------------------
__global__ __launch_bounds__(256) void finish_kernel(
    const float* __restrict__ x, const float* __restrict__ y,
    const float* __restrict__ wx_mlp, const float* __restrict__ bx_mlp,
    const float* __restrict__ wy_mlp, const float* __restrict__ by_mlp,
    const float* __restrict__ wfT,
    const float* __restrict__ Cred, float* __restrict__ out) {
  const int seg[16] = {0,1,1,1,2,2,2,2,2,3,3,3,3,3,3,3};
  __shared__ float sm[128];
  __shared__ float sg[2][128][4];
  int t = threadIdx.x;
  int bm = blockIdx.x;
  int mi = bm & 63;

  if (t < 128) sm[t] = Cred[(size_t)bm * 128 + t];  // [0:64)=mx, [64:128)=my
  __syncthreads();

  for (int st = 0; st < 2; ++st) {
    float v = 0.f;
    if (t < 128) {
      int side = t >> 6, j = t & 63;
      const float* wmlp = side ? wy_mlp : wx_mlp;
      const float* bmlp = side ? by_mlp : bx_mlp;
      const float* mv = sm + side * 64;
#pragma unroll 8
      for (int k = 0; k < 64; ++k)
        v += mv[k] * wmlp[(st * 64 + k) * 64 + j];
      v += bmlp[(st * 64 + mi) * 64 + j];
      v = v / (1.f + __expf(-v));
    }
    __syncthreads();
    if (t < 128) sm[t] = v;
    __syncthreads();
  }

  {  // gates: side wave-uniform, coalesced wfT reads
    int side = t >> 7, f = t & 127;
    const float* base = wfT + side * 32768;  // [k][l][f]
    const float* mv = sm + side * 64;
    float gg[4] = {0.f, 0.f, 0.f, 0.f};
#pragma unroll 8
    for (int k = 0; k < 64; ++k) {
      float m2 = mv[k];
#pragma unroll
      for (int l = 0; l < 4; ++l)
        gg[l] += m2 * base[(k * 4 + l) * 128 + f];
    }
#pragma unroll
    for (int l = 0; l < 4; ++l)
      sg[side][f][l] = gg[l] / (1.f + __expf(-gg[l]));
  }
  __syncthreads();

  {  // output: thread -> (f, half), 8 floats; fully coalesced
    int f = t >> 1, half = t & 1;
    size_t base = ((size_t)bm * 128 + f) * 16 + half * 8;
    float4 xa = *(const float4*)(x + base), xb4 = *(const float4*)(x + base + 4);
    float4 ya = *(const float4*)(y + base), yb4 = *(const float4*)(y + base + 4);
    float xv[8] = {xa.x, xa.y, xa.z, xa.w, xb4.x, xb4.y, xb4.z, xb4.w};
    float yv[8] = {ya.x, ya.y, ya.z, ya.w, yb4.x, yb4.y, yb4.z, yb4.w};
    float o[8];
#pragma unroll
    for (int ii = 0; ii < 8; ++ii) {
      int c = half * 8 + ii;
      o[ii] = sg[0][f][seg[c]] * xv[ii] + sg[1][f][seg[c]] * yv[ii];
    }
    *(float4*)(out + base)     = make_float4(o[0], o[1], o[2], o[3]);
    *(float4*)(out + base + 4) = make_float4(o[4], o[5], o[6], o[7]);
  }
}

// ---------------------------------------------------------------------------
extern "C" void kernel_launch(void* const* d_in, const int* in_sizes, int n_in,
                              void* d_out, int out_size, void* d_ws, size_t ws_size,
                              hipStream_t stream) {
  const float* x      = (const float*)d_in[0];
  const float* y      = (const float*)d_in[1];
  const float* wx0    = (const float*)d_in[2];
  const float* wy0    = (const float*)d_in[3];
  const float* wx_mlp = (const float*)d_in[4];
  const float* bx_mlp = (const float*)d_in[5];
  const float* wy_mlp = (const float*)d_in[6];
  const float* by_mlp = (const float*)d_in[7];
  const float* wxf    = (const float*)d_in[8];
  const float* wyf    = (const float*)d_in[9];
  float* out = (float*)d_out;

  uint16_t* Wb    = (uint16_t*)d_ws;                               // 16,777,216 B
  uint16_t* xb    = (uint16_t*)((char*)d_ws + (size_t)16777216);   //  4,194,304 B
  uint16_t* yb    = (uint16_t*)((char*)d_ws + (size_t)20971520);   //  4,194,304 B
  float*    Cpart = (float*)((char*)d_ws + (size_t)25165824);      // 67,108,864 B
  float*    wfT   = (float*)((char*)d_ws + (size_t)92274688);      //    262,144 B
  float*    Cred  = (float*)((char*)d_ws + (size_t)92536832);      //    524,288 B

  convert_all<<<6176, 256, 0, stream>>>(wx0, wy0, x, y, wxf, wyf, Wb, xb, yb, wfT);
  fused_gemm<<<dim3(128, 8), 256, 0, stream>>>(xb, yb, Wb, Cpart);
  reduce_kernel<<<1024, 256, 0, stream>>>(Cpart, Cred);
  finish_kernel<<<1024, 256, 0, stream>>>(x, y, wx_mlp, bx_mlp, wy_mlp, by_mlp,
                                          wfT, Cred, out);
}